// Round 13
// baseline (19095.265 us; speedup 1.0000x reference)
//
#include <hip/hip_runtime.h>
#include <math.h>

// NER BiLSTM-CRF on MI355X — chain-per-block recurrence, chunked gx, fused emissions.
// fp32 throughout (Viterbi argmax flips are fatal: tags threshold 4.82, range 0..8).
//
// The recurrence is independent per (batch, dir) = 128 chains. Per chunk k (64 steps):
//   gx_gemm (1024 blocks): gx[chain][s][1024] = emb[x[b][t_eff]] . Wih_d^T + bias_d
//     (t_eff = k*64+s fwd, 511-(k*64+s) bwd -> both directions consume s sequentially)
//   lstm_chain (128 blocks x 512 thr): one chain per block; Whh in VGPRs (128/thread);
//     h in LDS; c in regs; 2 barriers/step; emissions fused (9x256 dots into em_f/em_b).
// One stream serializes chunks anyway -> single gx buffer (33.5MB), no double buffer.
// NO cross-block sync, NO spins, NO atomics in this path -> deterministic.
// ws total ~37.7MB << proven-available 68.9MB. Fallback = round-7 kernel VERBATIM
// (r12 lesson: my "fallback copy" had drifted — release/poll mismatch -> livelock).
//
// ws layout (chain path):
//   gx     [128][64][1024] f32   33,554,432 @ 0
//   em_f   [64][512][9] f32       1,179,648 @ 33,554,432
//   em_b   [64][512][9] f32       1,179,648 @ 34,734,080
//   em     [512][64][9] f32       1,179,648 @ 35,913,728
//   carry_h[128][256] f32           131,072 @ 37,093,376
//   carry_c[128][256] f32           131,072 @ 37,224,448
//   last_tag [64] i32                   256 @ 37,355,520
//   hist   [64][512][9] u8          294,912 @ 37,355,776

#define Bv 64
#define Lv 512
#define CT 64   // chunk length (steps)

__device__ __forceinline__ float sigmoidf_(float x) { return 1.0f / (1.0f + expf(-x)); }

// ---------------- Phase 1 (per chunk): gx GEMM ----------------
// grid 1024: chain = bid>>3 (d=chain>>6, b=chain&63), nt = bid&7 (128-col N-tile).
// M = 64 steps (s), N = 128, K = 256.
__global__ __launch_bounds__(256) void gx_gemm(
    const int* __restrict__ x, const float* __restrict__ embed,
    const float* __restrict__ Wih_f, const float* __restrict__ Wih_b,
    const float* __restrict__ bf, const float* __restrict__ bb_,
    float* __restrict__ gx, int k0s)
{
    const int chain = blockIdx.x >> 3;
    const int nt = blockIdx.x & 7;
    const int tid = threadIdx.x;
    const int d = chain >> 6;
    const int b = chain & 63;

    const float* Wih  = d ? Wih_b : Wih_f;
    const float* bias = d ? bb_   : bf;

    __shared__ float A_lds[64][68];
    __shared__ float B_lds[128][65];
    __shared__ int   toks[64];

    if (tid < 64) {
        const int tt = k0s + tid;
        const int t_eff = d ? (Lv - 1 - tt) : tt;
        toks[tid] = x[b * Lv + t_eff];
    }
    __syncthreads();

    const int tm = tid >> 4;      // 0..15 -> 4 M rows each
    const int tn = tid & 15;      // 0..15 -> 8 N cols each
    float acc[4][8];
    #pragma unroll
    for (int mi = 0; mi < 4; ++mi)
        #pragma unroll
        for (int ni = 0; ni < 8; ++ni) acc[mi][ni] = 0.f;

    for (int kc = 0; kc < 4; ++kc) {
        {   // stage A: 64 step-rows x 64 K (gather by token)
            const int row = tid >> 2, fo = tid & 3;
            const float* src = embed + (size_t)toks[row] * 256 + kc * 64 + fo * 16;
            float4* dst = reinterpret_cast<float4*>(&A_lds[row][fo * 16]);
            #pragma unroll
            for (int j = 0; j < 4; ++j)
                dst[j] = *reinterpret_cast<const float4*>(src + 4 * j);
        }
        {   // stage B: 128 gate-rows x 64 K
            const int row = tid >> 1, ho = tid & 1;
            const float* src = Wih + (size_t)(nt * 128 + row) * 256 + kc * 64 + ho * 32;
            #pragma unroll
            for (int j = 0; j < 8; ++j)
                *reinterpret_cast<float4*>(&B_lds[row][ho * 32 + 4 * j]) =
                    *reinterpret_cast<const float4*>(src + 4 * j);
        }
        __syncthreads();
        #pragma unroll
        for (int k4 = 0; k4 < 16; ++k4) {
            float4 a4[4], b4[8];
            #pragma unroll
            for (int mi = 0; mi < 4; ++mi)
                a4[mi] = *reinterpret_cast<const float4*>(&A_lds[tm * 4 + mi][k4 * 4]);
            #pragma unroll
            for (int ni = 0; ni < 8; ++ni)
                b4[ni] = *reinterpret_cast<const float4*>(&B_lds[tn * 8 + ni][k4 * 4]);
            #pragma unroll
            for (int mi = 0; mi < 4; ++mi)
                #pragma unroll
                for (int ni = 0; ni < 8; ++ni)
                    acc[mi][ni] += a4[mi].x * b4[ni].x + a4[mi].y * b4[ni].y
                                 + a4[mi].z * b4[ni].z + a4[mi].w * b4[ni].w;
        }
        __syncthreads();
    }

    const int nbase = nt * 128 + tn * 8;
    float4 bias0 = *reinterpret_cast<const float4*>(bias + nbase);
    float4 bias1 = *reinterpret_cast<const float4*>(bias + nbase + 4);
    #pragma unroll
    for (int mi = 0; mi < 4; ++mi) {
        const int s = tm * 4 + mi;
        float4 o0 = make_float4(acc[mi][0] + bias0.x, acc[mi][1] + bias0.y,
                                acc[mi][2] + bias0.z, acc[mi][3] + bias0.w);
        float4 o1 = make_float4(acc[mi][4] + bias1.x, acc[mi][5] + bias1.y,
                                acc[mi][6] + bias1.z, acc[mi][7] + bias1.w);
        float* outp = gx + ((size_t)chain * CT + s) * 1024 + nbase;
        *reinterpret_cast<float4*>(outp)     = o0;
        *reinterpret_cast<float4*>(outp + 4) = o1;
    }
}

// ---------------- Phase 2 (per chunk): chain recurrence + fused emissions ----------
// 128 blocks x 512 threads. Thread (rt=tid&127, kt=tid>>7): Whh rows {rt+128i, i<8},
// K window [kt*64, kt*64+64) -> 128 VGPRs of weights. kt wave-uniform -> broadcast
// h_lds reads. Gate rows: r = q*256+u (q: 0=i,1=f,2=g,3=o).
__global__ __launch_bounds__(512, 2) void lstm_chain(
    const float* __restrict__ gx, const float* __restrict__ Whh_f,
    const float* __restrict__ Whh_b, const float* __restrict__ Wout,
    float* __restrict__ carry_h, float* __restrict__ carry_c,
    float* __restrict__ em_f, float* __restrict__ em_b, int k0s)
{
    const int chain = blockIdx.x;
    const int d = chain >> 6;
    const int b = chain & 63;
    const int tid = threadIdx.x;
    const int rt = tid & 127;
    const int kt = tid >> 7;
    const float* Whh = d ? Whh_b : Whh_f;

    __shared__ float h_lds[260];
    __shared__ float parts[4][1032];
    __shared__ float wout_lds[9][260];

    // Whh slice to VGPRs: 8 rows x 16 float4
    float4 whh[8][16];
    #pragma unroll
    for (int i = 0; i < 8; ++i) {
        const float* wr = Whh + (size_t)(rt + 128 * i) * 256 + kt * 64;
        #pragma unroll
        for (int m = 0; m < 16; ++m)
            whh[i][m] = *reinterpret_cast<const float4*>(wr + 4 * m);
    }
    // Wout slice (this direction's 256 cols)
    for (int i = tid; i < 9 * 256; i += 512)
        wout_lds[i >> 8][i & 255] = Wout[(i >> 8) * 512 + d * 256 + (i & 255)];

    // carry state in
    float creg = 0.f;
    if (tid < 256) {
        creg = carry_c[chain * 256 + tid];
        h_lds[tid] = carry_h[chain * 256 + tid];
    }
    // prefetch gx s=0
    float gxn[4] = {0.f, 0.f, 0.f, 0.f};
    if (tid < 256) {
        const float* gr = gx + (size_t)chain * CT * 1024;
        #pragma unroll
        for (int q = 0; q < 4; ++q) gxn[q] = gr[q * 256 + tid];
    }
    __syncthreads();   // h_lds + wout_lds ready

    for (int s = 0; s < CT; ++s) {
        // hh dot on h_lds (hidden state entering this step)
        float acc[8];
        #pragma unroll
        for (int i = 0; i < 8; ++i) acc[i] = 0.f;
        #pragma unroll
        for (int m = 0; m < 16; ++m) {
            const float4 hv = *reinterpret_cast<const float4*>(&h_lds[kt * 64 + 4 * m]);
            #pragma unroll
            for (int i = 0; i < 8; ++i) {
                const float4 wv = whh[i][m];
                acc[i] += wv.x * hv.x + wv.y * hv.y + wv.z * hv.z + wv.w * hv.w;
            }
        }
        // prefetch gx for s+1
        float gxf[4] = {0.f, 0.f, 0.f, 0.f};
        {
            const int s1 = (s + 1 < CT) ? s + 1 : CT - 1;
            if (tid < 256) {
                const float* gr = gx + ((size_t)chain * CT + s1) * 1024;
                #pragma unroll
                for (int q = 0; q < 4; ++q) gxf[q] = gr[q * 256 + tid];
            }
        }
        // write K-partials
        #pragma unroll
        for (int i = 0; i < 8; ++i) parts[kt][rt + 128 * i] = acc[i];
        __syncthreads();   // SYNC_B: parts ready; all h_lds reads of this step done

        if (tid < 256) {
            const int u = tid;
            float gv[4];
            #pragma unroll
            for (int q = 0; q < 4; ++q) {
                const int r = q * 256 + u;
                gv[q] = gxn[q] + parts[0][r] + parts[1][r] + parts[2][r] + parts[3][r];
            }
            creg = sigmoidf_(gv[1]) * creg + sigmoidf_(gv[0]) * tanhf(gv[2]);
            const float hval = sigmoidf_(gv[3]) * tanhf(creg);
            h_lds[u] = hval;
            #pragma unroll
            for (int q = 0; q < 4; ++q) gxn[q] = gxf[q];
        }
        __syncthreads();   // SYNC_A: h_lds = h output of this step

        // fused emission for position t_eff(k0s+s), reading h_lds just produced.
        // (next h_lds write is after next SYNC_B -> race-free)
        {
            const int tt = k0s + s;
            const int t_pos = d ? (Lv - 1 - tt) : tt;
            int j = -1, lane = 0;
            if (tid >= 256) { j = (tid - 256) >> 5; lane = (tid - 256) & 31; }
            else if (tid < 32) { j = 8; lane = tid; }
            if (j >= 0) {
                float s9 = 0.f;
                #pragma unroll
                for (int w = 0; w < 8; ++w) {
                    const int u = lane + 32 * w;
                    s9 += h_lds[u] * wout_lds[j][u];
                }
                s9 += __shfl_xor(s9, 1);
                s9 += __shfl_xor(s9, 2);
                s9 += __shfl_xor(s9, 4);
                s9 += __shfl_xor(s9, 8);
                s9 += __shfl_xor(s9, 16);
                if (lane == 0) {
                    float* em_arr = d ? em_b : em_f;
                    em_arr[((size_t)b * Lv + t_pos) * 9 + j] = s9;
                }
            }
        }
    }

    // carry state out
    if (tid < 256) {
        carry_c[chain * 256 + tid] = creg;
        carry_h[chain * 256 + tid] = h_lds[tid];
    }
}

// combine partial emissions -> em[t][b][j] (+bias), layout viterbi expects
__global__ __launch_bounds__(256) void em_combine(
    const float* __restrict__ em_f, const float* __restrict__ em_b,
    const float* __restrict__ bout, float* __restrict__ em)
{
    const int idx = blockIdx.x * 256 + threadIdx.x;   // < 64*512*9
    const int b = idx / (Lv * 9);
    const int rem = idx - b * (Lv * 9);
    const int t = rem / 9;
    const int j = rem - t * 9;
    const size_t src = ((size_t)b * Lv + t) * 9 + j;
    em[((size_t)t * 64 + b) * 9 + j] = em_f[src] + em_b[src] + bout[j];
}

// ---------------- Fallback: round-7 persistent kernel (VERBATIM) ----------------
__global__ __launch_bounds__(256, 1) void lstm_persist(
    const int* __restrict__ x, const float* __restrict__ embed,
    const float* __restrict__ Wih_f, const float* __restrict__ Whh_f, const float* __restrict__ bf,
    const float* __restrict__ Wih_b, const float* __restrict__ Whh_b, const float* __restrict__ bb_,
    float* __restrict__ h_glob, int* __restrict__ tags, float* __restrict__ h_hist)
{
    const int bid = blockIdx.x;
    const int g  = bid & 7;
    const int d  = g >> 2;
    const int bg = g & 3;
    const int ug = bid >> 3;
    const int tid = threadIdx.x;
    const int u0 = ug * 8;
    const int b0 = bg * 16;

    const float* Wih  = d ? Wih_b : Wih_f;
    const float* Whh  = d ? Whh_b : Whh_f;
    const float* bias = d ? bb_   : bf;

    const int tr = (tid >> 2) & 7;
    const int tb = tid & 3;
    const int k0 = (tid >> 5) * 32;

    __shared__ float wih_lds[32][260];
    __shared__ float h_lds[2][16][260];
    __shared__ float emb_lds[2][16][260];
    __shared__ float parts[4][32][17];
    __shared__ float bias_lds[32];

    {
        const int row = tid >> 3;
        const int seg = tid & 7;
        const int gq = row >> 3, j = row & 7;
        const float4* src = reinterpret_cast<const float4*>(
            Wih + ((size_t)(gq * 256 + u0 + j)) * 256 + seg * 32);
        float4* dst = reinterpret_cast<float4*>(&wih_lds[row][seg * 32]);
        #pragma unroll
        for (int q = 0; q < 8; ++q) dst[q] = src[q];
    }
    if (tid < 32) bias_lds[tid] = bias[(tid >> 3) * 256 + u0 + (tid & 7)];

    float4 whh[4][8];
    #pragma unroll
    for (int i = 0; i < 4; ++i) {
        const float* wr = Whh + ((size_t)(i * 256 + u0 + tr)) * 256 + k0;
        #pragma unroll
        for (int m = 0; m < 8; ++m) whh[i][m] = *reinterpret_cast<const float4*>(wr + 4 * m);
    }

    {
        const int b = tid >> 4, cseg = tid & 15;
        const int t0 = d ? (Lv - 1) : 0;
        const int xv = x[(b0 + b) * Lv + t0];
        const float4* src = reinterpret_cast<const float4*>(embed + (size_t)xv * 256 + cseg * 16);
        float4* dstp = reinterpret_cast<float4*>(&emb_lds[0][b][cseg * 16]);
        dstp[0] = src[0]; dstp[1] = src[1]; dstp[2] = src[2]; dstp[3] = src[3];
    }
    __syncthreads();

    float creg = 0.f;
    const int* my_tags = tags + ((g * 32 + (tid >> 3)) << 2);
    int* rel_tag = tags + ((g * 32 + ug) << 2) + (tid >> 6);

    for (int tt = 0; tt < Lv; ++tt) {
        const int par = tt & 1;

        float acc[4][4];
        #pragma unroll
        for (int i = 0; i < 4; ++i)
            #pragma unroll
            for (int u = 0; u < 4; ++u) acc[i][u] = 0.f;

        #pragma unroll
        for (int m = 0; m < 8; ++m) {
            float4 ev[4];
            #pragma unroll
            for (int u = 0; u < 4; ++u)
                ev[u] = *reinterpret_cast<const float4*>(&emb_lds[par][tb + 4 * u][k0 + 4 * m]);
            #pragma unroll
            for (int i = 0; i < 4; ++i) {
                float4 wv = *reinterpret_cast<const float4*>(&wih_lds[tr + 8 * i][k0 + 4 * m]);
                #pragma unroll
                for (int u = 0; u < 4; ++u)
                    acc[i][u] += wv.x * ev[u].x + wv.y * ev[u].y + wv.z * ev[u].z + wv.w * ev[u].w;
            }
        }

        if (tt + 1 < Lv) {
            const int b = tid >> 4, cseg = tid & 15;
            const int t1 = d ? (Lv - 2 - tt) : (tt + 1);
            const int xv = x[(b0 + b) * Lv + t1];
            const float4* src = reinterpret_cast<const float4*>(embed + (size_t)xv * 256 + cseg * 16);
            float4 e0 = src[0], e1 = src[1], e2 = src[2], e3 = src[3];
            float4* dstp = reinterpret_cast<float4*>(&emb_lds[par ^ 1][b][cseg * 16]);
            dstp[0] = e0; dstp[1] = e1; dstp[2] = e2; dstp[3] = e3;
        }

        if (tt > 0) {
            int4 tv; int it = 0;
            for (;;) {
                asm volatile("global_load_dwordx4 %0, %1, off sc0 sc1\n\ts_waitcnt vmcnt(0)"
                             : "=&v"(tv) : "v"(my_tags) : "memory");
                if (tv.x >= tt && tv.y >= tt && tv.z >= tt && tv.w >= tt) break;
                if (++it > 2) __builtin_amdgcn_s_sleep(2);
                if (it > (1 << 22)) break;
            }
            const float* hs = h_glob + ((size_t)(g * 2 + par)) * 4096 + tid * 16;
            float4 a0, a1, a2, a3;
            asm volatile(
                "global_load_dwordx4 %0, %4, off sc0 sc1\n\t"
                "global_load_dwordx4 %1, %4, off offset:16 sc0 sc1\n\t"
                "global_load_dwordx4 %2, %4, off offset:32 sc0 sc1\n\t"
                "global_load_dwordx4 %3, %4, off offset:48 sc0 sc1\n\t"
                "s_waitcnt vmcnt(0)"
                : "=&v"(a0), "=&v"(a1), "=&v"(a2), "=&v"(a3) : "v"(hs) : "memory");
            const int u = tid;
            h_lds[par][ 0][u] = a0.x; h_lds[par][ 1][u] = a0.y; h_lds[par][ 2][u] = a0.z; h_lds[par][ 3][u] = a0.w;
            h_lds[par][ 4][u] = a1.x; h_lds[par][ 5][u] = a1.y; h_lds[par][ 6][u] = a1.z; h_lds[par][ 7][u] = a1.w;
            h_lds[par][ 8][u] = a2.x; h_lds[par][ 9][u] = a2.y; h_lds[par][10][u] = a2.z; h_lds[par][11][u] = a2.w;
            h_lds[par][12][u] = a3.x; h_lds[par][13][u] = a3.y; h_lds[par][14][u] = a3.z; h_lds[par][15][u] = a3.w;
        }
        __syncthreads();

        if (tt > 0) {
            #pragma unroll
            for (int m = 0; m < 8; ++m) {
                float4 hv[4];
                #pragma unroll
                for (int u = 0; u < 4; ++u)
                    hv[u] = *reinterpret_cast<const float4*>(&h_lds[par][tb + 4 * u][k0 + 4 * m]);
                #pragma unroll
                for (int i = 0; i < 4; ++i) {
                    const float4 wv = whh[i][m];
                    #pragma unroll
                    for (int u = 0; u < 4; ++u)
                        acc[i][u] += wv.x * hv[u].x + wv.y * hv[u].y + wv.z * hv[u].z + wv.w * hv[u].w;
                }
            }
        }

        #pragma unroll
        for (int i = 0; i < 4; ++i)
            #pragma unroll
            for (int u = 0; u < 4; ++u)
                acc[i][u] += __shfl_xor(acc[i][u], 32);
        if ((tid & 32) == 0) {
            const int w = tid >> 6;
            #pragma unroll
            for (int i = 0; i < 4; ++i)
                #pragma unroll
                for (int u = 0; u < 4; ++u)
                    parts[w][tr + 8 * i][tb + 4 * u] = acc[i][u];
        }
        __syncthreads();

        float hval = 0.f;
        if (!(tid & 1)) {
            const int p  = tid >> 1;
            const int j  = p & 7;
            const int bb = p >> 3;
            float gv[4];
            #pragma unroll
            for (int q = 0; q < 4; ++q) {
                const int r = q * 8 + j;
                gv[q] = parts[0][r][bb] + parts[1][r][bb] + parts[2][r][bb] + parts[3][r][bb]
                      + bias_lds[r];
            }
            creg = sigmoidf_(gv[1]) * creg + sigmoidf_(gv[0]) * tanhf(gv[2]);
            hval = sigmoidf_(gv[3]) * tanhf(creg);
            float* dst = h_glob + ((size_t)(g * 2 + (par ^ 1))) * 4096 + (u0 + j) * 16 + bb;
            asm volatile("global_store_dword %0, %1, off sc0 sc1"
                         :: "v"(dst), "v"(hval) : "memory");
        }
        asm volatile("s_waitcnt vmcnt(0)" ::: "memory");
        if ((tid & 63) == 0) {
            int val = tt + 1;
            asm volatile("global_store_dword %0, %1, off sc0 sc1"
                         :: "v"(rel_tag), "v"(val) : "memory");
        }
        if (!(tid & 1)) {
            const int p  = tid >> 1;
            const int j  = p & 7;
            const int bb = p >> 3;
            const int t_eff = d ? (Lv - 1 - tt) : tt;
            h_hist[((size_t)(b0 + bb) * Lv + t_eff) * 512 + d * 256 + u0 + j] = hval;
        }
    }
}

__global__ __launch_bounds__(256) void emis_kernel(
    const float* __restrict__ h_hist, const float* __restrict__ Wout,
    const float* __restrict__ bout, float* __restrict__ em)
{
    const int l  = blockIdx.x >> 2;
    const int bg = blockIdx.x & 3;
    const int tid = threadIdx.x;
    __shared__ float w_lds[9][516];
    __shared__ float h_ldsx[16][512];

    for (int i = tid; i < 9 * 512; i += 256) w_lds[i >> 9][i & 511] = Wout[i];
    for (int i = tid; i < 16 * 128; i += 256) {
        const int bb = i >> 7; const int k = (i & 127) * 4;
        *reinterpret_cast<float4*>(&h_ldsx[bb][k]) =
            *reinterpret_cast<const float4*>(&h_hist[((size_t)(bg * 16 + bb) * 512 + l) * 512 + k]);
    }
    __syncthreads();

    const int bb = tid >> 4;
    const int j = tid & 15;
    if (j < 9) {
        float acc = bout[j];
        #pragma unroll 4
        for (int k = 0; k < 512; k += 4) {
            float4 hv = *reinterpret_cast<const float4*>(&h_ldsx[bb][k]);
            float4 wv = *reinterpret_cast<const float4*>(&w_lds[j][k]);
            acc += hv.x * wv.x + hv.y * wv.y + hv.z * wv.z + hv.w * wv.w;
        }
        em[((size_t)l * 64 + bg * 16 + bb) * 9 + j] = acc;
    }
}

// ---------------- Tail kernels (proven, unchanged) ----------------
__global__ __launch_bounds__(576) void viterbi_fwd(
    const float* __restrict__ em, const float* __restrict__ start,
    const float* __restrict__ trans, const float* __restrict__ endt,
    unsigned char* __restrict__ hist, int* __restrict__ last_tag,
    float* __restrict__ out_best)
{
    const int tid = threadIdx.x;
    const int b = tid / 9;
    const int j = tid - b * 9;
    __shared__ float sc[2][64][9];
    float t9[9];
    #pragma unroll
    for (int i = 0; i < 9; ++i) t9[i] = trans[i * 9 + j];

    sc[0][b][j] = start[j] + em[tid];
    float emv = em[(64 + b) * 9 + j];
    __syncthreads();
    for (int t = 1; t < 512; ++t) {
        float em_nxt = (t < 511) ? em[((t + 1) * 64 + b) * 9 + j] : 0.f;
        const int cur = t & 1, prv = cur ^ 1;
        float best = -1e30f; int arg = 0;
        #pragma unroll
        for (int i = 0; i < 9; ++i) {
            float v = sc[prv][b][i] + t9[i];
            if (v > best) { best = v; arg = i; }
        }
        best += emv;
        sc[cur][b][j] = best;
        hist[((size_t)b * 512 + t) * 9 + j] = (unsigned char)arg;
        __syncthreads();
        emv = em_nxt;
    }
    sc[1][b][j] += endt[j];
    __syncthreads();
    if (j == 0) {
        float best = -1e30f; int arg = 0;
        #pragma unroll
        for (int i = 0; i < 9; ++i) {
            float v = sc[1][b][i];
            if (v > best) { best = v; arg = i; }
        }
        out_best[b] = best;
        last_tag[b] = arg;
    }
}

__global__ __launch_bounds__(256) void backtrack(
    const unsigned char* __restrict__ hist, const int* __restrict__ last_tag,
    float* __restrict__ out_tags)
{
    const int b = blockIdx.x;
    const int tid = threadIdx.x;
    __shared__ __align__(16) unsigned char hl[512 * 9];
    const uint4* src = reinterpret_cast<const uint4*>(hist + (size_t)b * 512 * 9);
    uint4* dst = reinterpret_cast<uint4*>(hl);
    for (int i = tid; i < 512 * 9 / 16; i += 256) dst[i] = src[i];
    __syncthreads();
    if (tid == 0) {
        int tag = last_tag[b];
        out_tags[b * 512 + 511] = (float)tag;
        for (int t = 511; t >= 1; --t) {
            tag = hl[t * 9 + tag];
            out_tags[b * 512 + t - 1] = (float)tag;
        }
    }
}

extern "C" void kernel_launch(void* const* d_in, const int* in_sizes, int n_in,
                              void* d_out, int out_size, void* d_ws, size_t ws_size,
                              hipStream_t stream)
{
    const int*   x     = (const int*)d_in[0];
    const float* embed = (const float*)d_in[1];
    const float* Wih_f = (const float*)d_in[2];
    const float* Whh_f = (const float*)d_in[3];
    const float* bf    = (const float*)d_in[4];
    const float* Wih_b = (const float*)d_in[5];
    const float* Whh_b = (const float*)d_in[6];
    const float* bb    = (const float*)d_in[7];
    const float* Wout  = (const float*)d_in[8];
    const float* bout  = (const float*)d_in[9];
    const float* start = (const float*)d_in[10];
    const float* trans = (const float*)d_in[11];
    const float* endt  = (const float*)d_in[12];

    char* ws = (char*)d_ws;
    float* out = (float*)d_out;   // [64*512 tags][64 best], all f32

    const size_t NEED = 37650688ULL;   // chain-path footprint (see header)

    if (ws_size >= NEED) {
        float* gx      = (float*)ws;                          // 33,554,432
        float* em_f    = (float*)(ws + 33554432ULL);          //  1,179,648
        float* em_b    = (float*)(ws + 34734080ULL);          //  1,179,648
        float* em      = (float*)(ws + 35913728ULL);          //  1,179,648
        float* carry_h = (float*)(ws + 37093376ULL);          //    131,072
        float* carry_c = (float*)(ws + 37224448ULL);          //    131,072
        int*   last_tag = (int*)(ws + 37355520ULL);           //        256
        unsigned char* hist = (unsigned char*)(ws + 37355776ULL); // 294,912

        hipMemsetAsync(carry_h, 0, 262144, stream);   // h0 = c0 = 0

        for (int k = 0; k < Lv / CT; ++k) {
            gx_gemm<<<1024, 256, 0, stream>>>(x, embed, Wih_f, Wih_b, bf, bb, gx, k * CT);
            lstm_chain<<<128, 512, 0, stream>>>(gx, Whh_f, Whh_b, Wout,
                                                carry_h, carry_c, em_f, em_b, k * CT);
        }
        em_combine<<<1152, 256, 0, stream>>>(em_f, em_b, bout, em);
        viterbi_fwd<<<1, 576, 0, stream>>>(em, start, trans, endt, hist, last_tag, out + 64 * 512);
        backtrack<<<64, 256, 0, stream>>>(hist, last_tag, out);
    } else {
        // fallback: round-7 exchange-based path (verbatim)
        float* h_glob  = (float*)ws;                        // 262144 B
        int*   tags    = (int*)(ws + 262144);               // 4096 B
        float* h_hist  = (float*)(ws + 267264);             // 67108864 B
        float* em      = (float*)(ws + 267264 + 67108864);  // 1179648 B
        int*   last_tag = (int*)(ws + 68555776);            // 256 B
        unsigned char* hist = (unsigned char*)(ws + 68556032); // 294912 B

        hipMemsetAsync(tags, 0, 4096, stream);
        lstm_persist<<<256, 256, 0, stream>>>(x, embed, Wih_f, Whh_f, bf,
                                              Wih_b, Whh_b, bb,
                                              h_glob, tags, h_hist);
        emis_kernel<<<2048, 256, 0, stream>>>(h_hist, Wout, bout, em);
        viterbi_fwd<<<1, 576, 0, stream>>>(em, start, trans, endt, hist, last_tag, out + 64 * 512);
        backtrack<<<64, 256, 0, stream>>>(hist, last_tag, out);
    }
}

// Round 14
// 3661.781 us; speedup vs baseline: 5.2147x; 5.2147x over previous
//
#include <hip/hip_runtime.h>
#include <math.h>

// NER BiLSTM-CRF on MI355X — r7 persistent-exchange structure with STAMP-EMBEDDED
// h exchange (single one-way trip replaces store->drain->tag->poll->load).
// fp32 throughout (Viterbi argmax flips are fatal: tags threshold 4.82, range 0..8).
//
// 256 blocks of 256 threads, 1/CU (~108 KB LDS -> guaranteed residency).
// g=bid&7 (sync group: d=g>>2, bg=g&3, 16 batches), ug=bid>>3 (8 units).
// All cross-block traffic sc0 sc1 (system scope; r6: sc0-alone = stale L1 livelock).
// All asm loads wait vmcnt(0) INSIDE the issuing asm block; outputs early-clobbered
// (r8/r10: asm-loaded regs must never cross compiler-visible code unwaited).
// r13 lesson: 512 floats/thread of weights = 512 VGPRs (spills); a chain's Whh (1MB)
// exceeds a CU register file (512KB) -> unit-distributed design is forced.
//
// Exchange protocol (replaces r7 tags):
//   producer (pointwise thread): store (h, stamp=tt+1) as one dwordx2 sc0sc1. Done.
//   consumer fill: loop { 8x dwordx4 + vmcnt(0) in one asm -> 16 (h,stamp) pairs;
//                         accept iff all stamps == tt }.
//   WAR: stamp v+2 is written only after the writer's fill saw all-v+1 stamps,
//   which are published only after each block's v-read. Stale stamps are always
//   < tt (0 after per-call memset), never >, so ==tt is exact and safe.
//
// ws: h_hist [64 b][512 l][512 h] f32   67,108,864 @ 0
//     h2     [8 g][2 par][256 u][16 b][2] f32  524,288 @ 67,108,864  (dead after lstm)
//     em     [512][64][9] f32            1,179,648 @ 67,108,864  (overlaps h2; written after)
//     last_tag [64] i32                        256 @ 68,288,512
//     hist   [64][512][9] u8               294,912 @ 68,288,768
//     total 68,583,680 B  (< 68.85 MB proven available)

#define Bv 64
#define Lv 512

__device__ __forceinline__ float sigmoidf_(float x) { return 1.0f / (1.0f + expf(-x)); }

__global__ __launch_bounds__(256, 1) void lstm_persist(
    const int* __restrict__ x, const float* __restrict__ embed,
    const float* __restrict__ Wih_f, const float* __restrict__ Whh_f, const float* __restrict__ bf,
    const float* __restrict__ Wih_b, const float* __restrict__ Whh_b, const float* __restrict__ bb_,
    float* __restrict__ h2, float* __restrict__ h_hist)
{
    const int bid = blockIdx.x;
    const int g  = bid & 7;           // sync group
    const int d  = g >> 2;            // direction
    const int bg = g & 3;             // batch group (16 batches)
    const int ug = bid >> 3;          // unit group (8 units)
    const int tid = threadIdx.x;
    const int u0 = ug * 8;
    const int b0 = bg * 16;

    const float* Wih  = d ? Wih_b : Wih_f;
    const float* Whh  = d ? Whh_b : Whh_f;
    const float* bias = d ? bb_   : bf;

    // dot tiling: tid = ks*32 + tr*4 + tb (8 ksegs of K=32, 8 row-slots, 4 batch-slots)
    const int tr = (tid >> 2) & 7;
    const int tb = tid & 3;
    const int k0 = (tid >> 5) * 32;

    __shared__ float wih_lds[32][260];
    __shared__ float h_lds[2][16][260];
    __shared__ float emb_lds[2][16][260];
    __shared__ float parts[4][32][17];
    __shared__ float bias_lds[32];

    // ---- stage Wih slice to LDS ----
    {
        const int row = tid >> 3;     // 0..31
        const int seg = tid & 7;      // 32 floats each
        const int gq = row >> 3, j = row & 7;
        const float4* src = reinterpret_cast<const float4*>(
            Wih + ((size_t)(gq * 256 + u0 + j)) * 256 + seg * 32);
        float4* dst = reinterpret_cast<float4*>(&wih_lds[row][seg * 32]);
        #pragma unroll
        for (int q = 0; q < 8; ++q) dst[q] = src[q];
    }
    if (tid < 32) bias_lds[tid] = bias[(tid >> 3) * 256 + u0 + (tid & 7)];

    // ---- Whh slice to registers: rows {i*256+u0+tr}, k in [k0,k0+32) = 128 VGPRs ----
    float4 whh[4][8];
    #pragma unroll
    for (int i = 0; i < 4; ++i) {
        const float* wr = Whh + ((size_t)(i * 256 + u0 + tr)) * 256 + k0;
        #pragma unroll
        for (int m = 0; m < 8; ++m) whh[i][m] = *reinterpret_cast<const float4*>(wr + 4 * m);
    }

    // prologue: emb for step 0 into emb_lds[0]
    {
        const int b = tid >> 4, cseg = tid & 15;
        const int t0 = d ? (Lv - 1) : 0;
        const int xv = x[(b0 + b) * Lv + t0];
        const float4* src = reinterpret_cast<const float4*>(embed + (size_t)xv * 256 + cseg * 16);
        float4* dstp = reinterpret_cast<float4*>(&emb_lds[0][b][cseg * 16]);
        dstp[0] = src[0]; dstp[1] = src[1]; dstp[2] = src[2]; dstp[3] = src[3];
    }
    __syncthreads();

    float creg = 0.f;   // cell state for even threads: p=tid>>1 -> unit u0+(p&7), batch b0+(p>>3)

    for (int tt = 0; tt < Lv; ++tt) {
        const int par = tt & 1;

        // ---- 1. gx dot: wih(LDS) . emb_lds[par] ----
        float acc[4][4];
        #pragma unroll
        for (int i = 0; i < 4; ++i)
            #pragma unroll
            for (int u = 0; u < 4; ++u) acc[i][u] = 0.f;
        #pragma unroll
        for (int m = 0; m < 8; ++m) {
            float4 ev[4];
            #pragma unroll
            for (int u = 0; u < 4; ++u)
                ev[u] = *reinterpret_cast<const float4*>(&emb_lds[par][tb + 4 * u][k0 + 4 * m]);
            #pragma unroll
            for (int i = 0; i < 4; ++i) {
                float4 wv = *reinterpret_cast<const float4*>(&wih_lds[tr + 8 * i][k0 + 4 * m]);
                #pragma unroll
                for (int u = 0; u < 4; ++u)
                    acc[i][u] += wv.x * ev[u].x + wv.y * ev[u].y + wv.z * ev[u].z + wv.w * ev[u].w;
            }
        }

        // ---- 2. stage emb for tt+1 (overlaps the fill wait below) ----
        if (tt + 1 < Lv) {
            const int b = tid >> 4, cseg = tid & 15;
            const int t1 = d ? (Lv - 2 - tt) : (tt + 1);
            const int xv = x[(b0 + b) * Lv + t1];
            const float4* src = reinterpret_cast<const float4*>(embed + (size_t)xv * 256 + cseg * 16);
            float4 e0 = src[0], e1 = src[1], e2 = src[2], e3 = src[3];
            float4* dstp = reinterpret_cast<float4*>(&emb_lds[par ^ 1][b][cseg * 16]);
            dstp[0] = e0; dstp[1] = e1; dstp[2] = e2; dstp[3] = e3;
        }

        // ---- 3. stamp-fill: load own 16 (h,stamp) pairs until all stamps == tt ----
        if (tt > 0) {
            const float* hs = h2 + ((size_t)(g * 2 + par)) * 8192 + (size_t)tid * 32;
            float4 a0, a1, a2, a3, a4, a5, a6, a7;
            int it = 0;
            for (;;) {
                asm volatile(
                    "global_load_dwordx4 %0, %8, off sc0 sc1\n\t"
                    "global_load_dwordx4 %1, %8, off offset:16 sc0 sc1\n\t"
                    "global_load_dwordx4 %2, %8, off offset:32 sc0 sc1\n\t"
                    "global_load_dwordx4 %3, %8, off offset:48 sc0 sc1\n\t"
                    "global_load_dwordx4 %4, %8, off offset:64 sc0 sc1\n\t"
                    "global_load_dwordx4 %5, %8, off offset:80 sc0 sc1\n\t"
                    "global_load_dwordx4 %6, %8, off offset:96 sc0 sc1\n\t"
                    "global_load_dwordx4 %7, %8, off offset:112 sc0 sc1\n\t"
                    "s_waitcnt vmcnt(0)"
                    : "=&v"(a0), "=&v"(a1), "=&v"(a2), "=&v"(a3),
                      "=&v"(a4), "=&v"(a5), "=&v"(a6), "=&v"(a7)
                    : "v"(hs) : "memory");
                int ok = (__float_as_int(a0.y) == tt) & (__float_as_int(a0.w) == tt)
                       & (__float_as_int(a1.y) == tt) & (__float_as_int(a1.w) == tt)
                       & (__float_as_int(a2.y) == tt) & (__float_as_int(a2.w) == tt)
                       & (__float_as_int(a3.y) == tt) & (__float_as_int(a3.w) == tt)
                       & (__float_as_int(a4.y) == tt) & (__float_as_int(a4.w) == tt)
                       & (__float_as_int(a5.y) == tt) & (__float_as_int(a5.w) == tt)
                       & (__float_as_int(a6.y) == tt) & (__float_as_int(a6.w) == tt)
                       & (__float_as_int(a7.y) == tt) & (__float_as_int(a7.w) == tt);
                if (ok) break;
                if (++it > 2) __builtin_amdgcn_s_sleep(1);
                if (it > (1 << 22)) break;   // failsafe (never hit when resident)
            }
            const int u = tid;   // h for unit u, batches 0..15 (pairs)
            h_lds[par][ 0][u] = a0.x; h_lds[par][ 1][u] = a0.z;
            h_lds[par][ 2][u] = a1.x; h_lds[par][ 3][u] = a1.z;
            h_lds[par][ 4][u] = a2.x; h_lds[par][ 5][u] = a2.z;
            h_lds[par][ 6][u] = a3.x; h_lds[par][ 7][u] = a3.z;
            h_lds[par][ 8][u] = a4.x; h_lds[par][ 9][u] = a4.z;
            h_lds[par][10][u] = a5.x; h_lds[par][11][u] = a5.z;
            h_lds[par][12][u] = a6.x; h_lds[par][13][u] = a6.z;
            h_lds[par][14][u] = a7.x; h_lds[par][15][u] = a7.z;
        }
        __syncthreads();   // SYNC_A: h_lds[par] ready, emb_lds[par^1] ready

        // ---- 4. hh dot: whh(regs) . h_lds[par] ----
        if (tt > 0) {
            #pragma unroll
            for (int m = 0; m < 8; ++m) {
                float4 hv[4];
                #pragma unroll
                for (int u = 0; u < 4; ++u)
                    hv[u] = *reinterpret_cast<const float4*>(&h_lds[par][tb + 4 * u][k0 + 4 * m]);
                #pragma unroll
                for (int i = 0; i < 4; ++i) {
                    const float4 wv = whh[i][m];
                    #pragma unroll
                    for (int u = 0; u < 4; ++u)
                        acc[i][u] += wv.x * hv[u].x + wv.y * hv[u].y + wv.z * hv[u].z + wv.w * hv[u].w;
                }
            }
        }

        // ---- 5. reduce ksegs: shfl pair (bit5), 4 wave-partials to LDS ----
        #pragma unroll
        for (int i = 0; i < 4; ++i)
            #pragma unroll
            for (int u = 0; u < 4; ++u)
                acc[i][u] += __shfl_xor(acc[i][u], 32);
        if ((tid & 32) == 0) {
            const int w = tid >> 6;
            #pragma unroll
            for (int i = 0; i < 4; ++i)
                #pragma unroll
                for (int u = 0; u < 4; ++u)
                    parts[w][tr + 8 * i][tb + 4 * u] = acc[i][u];
        }
        __syncthreads();   // SYNC_B: parts ready

        // ---- 6. pointwise on even threads: unit u0+(p&7), batch b0+(p>>3) ----
        float hval = 0.f;
        if (!(tid & 1)) {
            const int p  = tid >> 1;
            const int j  = p & 7;
            const int bb = p >> 3;
            float gv[4];
            #pragma unroll
            for (int q = 0; q < 4; ++q) {
                const int r = q * 8 + j;
                gv[q] = parts[0][r][bb] + parts[1][r][bb] + parts[2][r][bb] + parts[3][r][bb]
                      + bias_lds[r];
            }
            creg = sigmoidf_(gv[1]) * creg + sigmoidf_(gv[0]) * tanhf(gv[2]);
            hval = sigmoidf_(gv[3]) * tanhf(creg);
            // store (h, stamp=tt+1) as one 8B transaction; self-validating, no drain/tag
            int2 pv; pv.x = __float_as_int(hval); pv.y = tt + 1;
            float* dst = h2 + ((size_t)(g * 2 + (par ^ 1))) * 8192
                       + (size_t)(((u0 + j) << 4) + bb) * 2;
            asm volatile("global_store_dwordx2 %0, %1, off sc0 sc1"
                         :: "v"(dst), "v"(pv) : "memory");
            // h_hist store off the critical path (plain cached store)
            const int t_eff = d ? (Lv - 1 - tt) : tt;
            h_hist[((size_t)(b0 + bb) * Lv + t_eff) * 512 + d * 256 + u0 + j] = hval;
        }
    }
}

// emissions: em[l][b][j] = dot(h_hist[b][l][:512], Wout[j]) + bout[j]
__global__ __launch_bounds__(256) void emis_kernel(
    const float* __restrict__ h_hist, const float* __restrict__ Wout,
    const float* __restrict__ bout, float* __restrict__ em)
{
    const int l  = blockIdx.x >> 2;
    const int bg = blockIdx.x & 3;
    const int tid = threadIdx.x;
    __shared__ float w_lds[9][516];
    __shared__ float h_ldsx[16][512];

    for (int i = tid; i < 9 * 512; i += 256) w_lds[i >> 9][i & 511] = Wout[i];
    for (int i = tid; i < 16 * 128; i += 256) {
        const int bb = i >> 7; const int k = (i & 127) * 4;
        *reinterpret_cast<float4*>(&h_ldsx[bb][k]) =
            *reinterpret_cast<const float4*>(&h_hist[((size_t)(bg * 16 + bb) * 512 + l) * 512 + k]);
    }
    __syncthreads();

    const int bb = tid >> 4;
    const int j = tid & 15;
    if (j < 9) {
        float acc = bout[j];
        #pragma unroll 4
        for (int k = 0; k < 512; k += 4) {
            float4 hv = *reinterpret_cast<const float4*>(&h_ldsx[bb][k]);
            float4 wv = *reinterpret_cast<const float4*>(&w_lds[j][k]);
            acc += hv.x * wv.x + hv.y * wv.y + hv.z * wv.z + hv.w * wv.w;
        }
        em[((size_t)l * 64 + bg * 16 + bb) * 9 + j] = acc;
    }
}

__global__ __launch_bounds__(576) void viterbi_fwd(
    const float* __restrict__ em, const float* __restrict__ start,
    const float* __restrict__ trans, const float* __restrict__ endt,
    unsigned char* __restrict__ hist, int* __restrict__ last_tag,
    float* __restrict__ out_best)
{
    const int tid = threadIdx.x;
    const int b = tid / 9;
    const int j = tid - b * 9;
    __shared__ float sc[2][64][9];
    float t9[9];
    #pragma unroll
    for (int i = 0; i < 9; ++i) t9[i] = trans[i * 9 + j];

    sc[0][b][j] = start[j] + em[tid];
    float emv = em[(64 + b) * 9 + j];
    __syncthreads();
    for (int t = 1; t < 512; ++t) {
        float em_nxt = (t < 511) ? em[((t + 1) * 64 + b) * 9 + j] : 0.f;
        const int cur = t & 1, prv = cur ^ 1;
        float best = -1e30f; int arg = 0;
        #pragma unroll
        for (int i = 0; i < 9; ++i) {
            float v = sc[prv][b][i] + t9[i];
            if (v > best) { best = v; arg = i; }
        }
        best += emv;
        sc[cur][b][j] = best;
        hist[((size_t)b * 512 + t) * 9 + j] = (unsigned char)arg;
        __syncthreads();
        emv = em_nxt;
    }
    sc[1][b][j] += endt[j];
    __syncthreads();
    if (j == 0) {
        float best = -1e30f; int arg = 0;
        #pragma unroll
        for (int i = 0; i < 9; ++i) {
            float v = sc[1][b][i];
            if (v > best) { best = v; arg = i; }
        }
        out_best[b] = best;
        last_tag[b] = arg;
    }
}

__global__ __launch_bounds__(256) void backtrack(
    const unsigned char* __restrict__ hist, const int* __restrict__ last_tag,
    float* __restrict__ out_tags)
{
    const int b = blockIdx.x;
    const int tid = threadIdx.x;
    __shared__ __align__(16) unsigned char hl[512 * 9];
    const uint4* src = reinterpret_cast<const uint4*>(hist + (size_t)b * 512 * 9);
    uint4* dst = reinterpret_cast<uint4*>(hl);
    for (int i = tid; i < 512 * 9 / 16; i += 256) dst[i] = src[i];
    __syncthreads();
    if (tid == 0) {
        int tag = last_tag[b];
        out_tags[b * 512 + 511] = (float)tag;
        for (int t = 511; t >= 1; --t) {
            tag = hl[t * 9 + tag];
            out_tags[b * 512 + t - 1] = (float)tag;
        }
    }
}

extern "C" void kernel_launch(void* const* d_in, const int* in_sizes, int n_in,
                              void* d_out, int out_size, void* d_ws, size_t ws_size,
                              hipStream_t stream)
{
    const int*   x     = (const int*)d_in[0];
    const float* embed = (const float*)d_in[1];
    const float* Wih_f = (const float*)d_in[2];
    const float* Whh_f = (const float*)d_in[3];
    const float* bf    = (const float*)d_in[4];
    const float* Wih_b = (const float*)d_in[5];
    const float* Whh_b = (const float*)d_in[6];
    const float* bb    = (const float*)d_in[7];
    const float* Wout  = (const float*)d_in[8];
    const float* bout  = (const float*)d_in[9];
    const float* start = (const float*)d_in[10];
    const float* trans = (const float*)d_in[11];
    const float* endt  = (const float*)d_in[12];

    char* ws = (char*)d_ws;
    float* h_hist = (float*)ws;                            // 67,108,864 B @ 0
    float* h2     = (float*)(ws + 67108864ULL);            // 524,288 B (dead after lstm)
    float* em     = (float*)(ws + 67108864ULL);            // 1,179,648 B (overlaps h2)
    int*   last_tag = (int*)(ws + 68288512ULL);            // 256 B
    unsigned char* hist = (unsigned char*)(ws + 68288768ULL); // 294,912 B

    float* out = (float*)d_out;   // [64*512 tags][64 best], all f32

    hipMemsetAsync(h2, 0, 524288, stream);   // zero stamps (kills cross-call leftovers)

    lstm_persist<<<256, 256, 0, stream>>>(x, embed, Wih_f, Whh_f, bf,
                                          Wih_b, Whh_b, bb, h2, h_hist);
    emis_kernel<<<2048, 256, 0, stream>>>(h_hist, Wout, bout, em);
    viterbi_fwd<<<1, 576, 0, stream>>>(em, start, trans, endt, hist, last_tag, out + 64 * 512);
    backtrack<<<64, 256, 0, stream>>>(hist, last_tag, out);
}